// Round 8
// baseline (468.976 us; speedup 1.0000x reference)
//
#include <hip/hip_runtime.h>
#include <hip/hip_bf16.h>

typedef __hip_bfloat16 bf16;
typedef __attribute__((ext_vector_type(8))) short short8;   // 8 bf16 = 4 VGPRs (MFMA A/B frag)
typedef __attribute__((ext_vector_type(4))) float f32x4;    // MFMA C/D frag

#define B_   8
#define S_   1024
#define D_   768
#define H_   12
#define HD_  64
#define MLP_ 3072
#define SD_  (S_ * D_)          // 786432 elements per batch

#define QSCALE 0.18033688011112042f   // log2(e) / 8  (softmax scale folded into q)

__device__ __forceinline__ float b2f(short h) {
  union { unsigned u; float f; } w;
  w.u = ((unsigned)(unsigned short)h) << 16;
  return w.f;
}

// async global->LDS, 16B per lane; LDS dest must equal wave-uniform base + lane*16B
__device__ __forceinline__ void gl2lds16(const bf16* g, bf16* l) {
  __builtin_amdgcn_global_load_lds(
      (const __attribute__((address_space(1))) unsigned*)(const void*)g,
      (__attribute__((address_space(3))) unsigned*)(void*)l, 16, 0, 0);
}

// ---------------------------------------------------------------------------
// all 4 weight transposes (fp32 [R][C] -> bf16 [C][R]) in one launch
// ---------------------------------------------------------------------------
__global__ __launch_bounds__(256) void transpose_all(
    const float* __restrict__ w_qkv, const float* __restrict__ w_out,
    const float* __restrict__ w1, const float* __restrict__ w2,
    bf16* __restrict__ t_qkv, bf16* __restrict__ t_out,
    bf16* __restrict__ t1, bf16* __restrict__ t2) {
  const int t = blockIdx.x;
  const float* in; bf16* out; int R, C, idx;
  if (t < 1728)      { in = w_qkv; out = t_qkv; R = 768;  C = 2304; idx = t; }
  else if (t < 2304) { in = w_out; out = t_out; R = 768;  C = 768;  idx = t - 1728; }
  else if (t < 4608) { in = w1;    out = t1;    R = 768;  C = 3072; idx = t - 2304; }
  else               { in = w2;    out = t2;    R = 3072; C = 768;  idx = t - 4608; }
  const int nbx = C >> 5;
  const int bx = (idx % nbx) * 32, by = (idx / nbx) * 32;
  __shared__ float tt[32][33];
  const int tx = threadIdx.x & 31, ty = threadIdx.x >> 5;  // ty: 0..7
#pragma unroll
  for (int rr = 0; rr < 32; rr += 8)
    tt[ty + rr][tx] = in[(long)(by + ty + rr) * C + bx + tx];
  __syncthreads();
#pragma unroll
  for (int rr = 0; rr < 32; rr += 8)
    out[(long)(bx + ty + rr) * R + by + tx] = __float2bfloat16(tt[tx][ty + rr]);
}

// ---------------------------------------------------------------------------
// instance-norm stats partials (768 blocks) + colsum(wt1) (48 blocks, reads
// the bf16-transposed w1 -> row-contiguous, 4 lanes per row)
// ---------------------------------------------------------------------------
__global__ __launch_bounds__(256) void stats_partial(const float* __restrict__ x,
                                                     float* __restrict__ redp,
                                                     const bf16* __restrict__ wt1,
                                                     float* __restrict__ cs1) {
  if (blockIdx.x >= 768) {                       // colsum over K of w1 (via wt1 rows)
    const int bi = blockIdx.x - 768;             // 0..47
    const int row = bi * 64 + (threadIdx.x >> 2);
    const int part = threadIdx.x & 3;
    const bf16* wr = wt1 + (long)row * 768 + part * 192;
    float s = 0.f;
#pragma unroll
    for (int u = 0; u < 24; ++u) {
      short8 v = *(const short8*)(wr + u * 8);
#pragma unroll
      for (int e = 0; e < 8; ++e) s += b2f(v[e]);
    }
    s += __shfl_xor(s, 1, 64);
    s += __shfl_xor(s, 2, 64);
    if (part == 0) cs1[row] = s;
    return;
  }
  const long off = (long)blockIdx.x * 8192;
  float s = 0.f, s2 = 0.f;
#pragma unroll
  for (int it = 0; it < 8; ++it) {
    float4 v = *(const float4*)(x + off + ((long)threadIdx.x + it * 256) * 4);
    s += v.x + v.y + v.z + v.w;
    s2 += v.x * v.x + v.y * v.y + v.z * v.z + v.w * v.w;
  }
#pragma unroll
  for (int o = 1; o < 64; o <<= 1) { s += __shfl_xor(s, o, 64); s2 += __shfl_xor(s2, o, 64); }
  __shared__ float sh[8];
  const int wave = threadIdx.x >> 6, lane = threadIdx.x & 63;
  if (lane == 0) { sh[wave * 2] = s; sh[wave * 2 + 1] = s2; }
  __syncthreads();
  if (threadIdx.x == 0) {
    redp[blockIdx.x * 2]     = sh[0] + sh[2] + sh[4] + sh[6];
    redp[blockIdx.x * 2 + 1] = sh[1] + sh[3] + sh[5] + sh[7];
  }
}

// reduce 96 partials per batch -> raw sums red_x[b*2..]; also zero red2
__global__ __launch_bounds__(512) void stats_final(const float* __restrict__ redp,
                                                   float* __restrict__ red_x,
                                                   float* __restrict__ red2) {
  const int b = threadIdx.x >> 6, lane = threadIdx.x & 63;
  const int i0 = (b * 96 + lane) * 2;
  float s  = redp[i0]     + ((lane < 32) ? redp[i0 + 128]     : 0.f);
  float s2 = redp[i0 + 1] + ((lane < 32) ? redp[i0 + 128 + 1] : 0.f);
#pragma unroll
  for (int o = 1; o < 64; o <<= 1) { s += __shfl_xor(s, o, 64); s2 += __shfl_xor(s2, o, 64); }
  if (lane == 0) { red_x[b * 2] = s; red_x[b * 2 + 1] = s2; }
  if (threadIdx.x < 16) red2[threadIdx.x] = 0.f;
}

// normalize fp32 input -> bf16, computing mean/rstd from raw sums
__global__ __launch_bounds__(256) void norm_k(const float* __restrict__ x,
                                              const float* __restrict__ sums,
                                              bf16* __restrict__ h) {
  const long i = ((long)blockIdx.x * 256 + threadIdx.x) * 8;
  const int b = (int)(i / SD_);
  const float mu = sums[b * 2] * (1.0f / SD_);
  const float var = sums[b * 2 + 1] * (1.0f / SD_) - mu * mu;
  const float rs = rsqrtf(var + 1e-5f);
  float4 v0 = *(const float4*)(x + i);
  float4 v1 = *(const float4*)(x + i + 4);
  __align__(16) bf16 tmp[8];
  tmp[0] = __float2bfloat16((v0.x - mu) * rs);
  tmp[1] = __float2bfloat16((v0.y - mu) * rs);
  tmp[2] = __float2bfloat16((v0.z - mu) * rs);
  tmp[3] = __float2bfloat16((v0.w - mu) * rs);
  tmp[4] = __float2bfloat16((v1.x - mu) * rs);
  tmp[5] = __float2bfloat16((v1.y - mu) * rs);
  tmp[6] = __float2bfloat16((v1.z - mu) * rs);
  tmp[7] = __float2bfloat16((v1.w - mu) * rs);
  *(short8*)(h + i) = *(const short8*)tmp;
}

// ---------------------------------------------------------------------------
// MFMA GEMM: TM=128, TN=64, BK=64. A staged in LDS (dbuf, 32 KB, XOR-swizzled);
// B (weights) streamed DIRECTLY global->registers with one-iteration prefetch
// (AITER-style) — removes 1/3 of LDS traffic, which R7 showed is the binding
// resource. 4 blocks/CU via __launch_bounds__(256,4).
// EPI 0: QKV scatter (outb0=q*QSCALE [B,H,S,HD], outb1=k, outb2=vT[B,H,HD,S])
// EPI 1: v = acc+bias+res; outf fp32, outb0 bf16 copy (+ fused IN-stats)
// EPI 2: v = rs*(acc - mu*cs[n]) + bias (IN folded as affine); gelu; outb0 bf16
// EPI 3: v = acc+bias+res; outf fp32 only
// ---------------------------------------------------------------------------
template <int EPI, bool STATS>
__global__ __launch_bounds__(256, 4) void gemm_k(
    const bf16* __restrict__ A, const bf16* __restrict__ Bt,
    int M, int N, int K,
    const float* __restrict__ biasf, const float* __restrict__ resf,
    const float* __restrict__ cs, const float* __restrict__ stat_in,
    float* __restrict__ outf,
    bf16* __restrict__ outb0, bf16* __restrict__ outb1, bf16* __restrict__ outb2,
    float* __restrict__ statp) {
  __shared__ __align__(16) bf16 As[2][128 * 64];
  __shared__ float sred[8];
  const int tid = threadIdx.x;
  const int bm = blockIdx.x * 128, bn = blockIdx.y * 64;
  const int wave = tid >> 6, lane = tid & 63;
  const int quad = lane >> 4, l16 = lane & 15;
  const int wm = (wave >> 1) * 64, wn = (wave & 1) * 32;
  const int swz = l16 & 7;            // row&7 for all fragment rows

  f32x4 acc[4][2];
#pragma unroll
  for (int i = 0; i < 4; ++i)
#pragma unroll
    for (int j = 0; j < 2; ++j) acc[i][j] = (f32x4){0.f, 0.f, 0.f, 0.f};

  const int srow = tid >> 3;                 // 0..31
  const int sgc = (tid & 7) ^ (srow & 7);    // swizzled global chunk for this LDS slot
  const bf16* Ab = A + (long)(bm + srow) * K + sgc * 8;

  auto stageA = [&](int buf, int k0) {
#pragma unroll
    for (int s = 0; s < 4; ++s)
      gl2lds16(Ab + (long)(s * 32) * K + k0, &As[buf][0] + s * 2048 + tid * 8);
  };

  // B direct-from-global fragment base pointers (weights, L2-resident)
  const bf16* Bg0 = Bt + (long)(bn + wn + l16) * K + quad * 8;
  const bf16* Bg1 = Bg0 + (long)16 * K;

  short8 bcur[2][2], bnxt[2][2];
#pragma unroll
  for (int kk = 0; kk < 2; ++kk) {
    bcur[kk][0] = *(const short8*)(Bg0 + kk * 32);
    bcur[kk][1] = *(const short8*)(Bg1 + kk * 32);
  }
  stageA(0, 0);
  const int nk = K >> 6;
  for (int kt = 0; kt < nk; ++kt) {
    const int cur = kt & 1;
    __syncthreads();                  // As[cur] staged (vmcnt drain); As[cur^1] free
    if (kt + 1 < nk) {
      stageA(cur ^ 1, (kt + 1) * 64);
      const int k1 = (kt + 1) * 64;
#pragma unroll
      for (int kk = 0; kk < 2; ++kk) {
        bnxt[kk][0] = *(const short8*)(Bg0 + k1 + kk * 32);
        bnxt[kk][1] = *(const short8*)(Bg1 + k1 + kk * 32);
      }
    }
    short8 a[2][4];
#pragma unroll
    for (int kk = 0; kk < 2; ++kk) {
      const int co = ((kk * 4 + quad) ^ swz) * 8;
#pragma unroll
      for (int i = 0; i < 4; ++i)
        a[kk][i] = *(const short8*)(&As[cur][0] + (wm + i * 16 + l16) * 64 + co);
    }
#pragma unroll
    for (int kk = 0; kk < 2; ++kk)
#pragma unroll
      for (int i = 0; i < 4; ++i)
#pragma unroll
        for (int j = 0; j < 2; ++j)
          acc[i][j] = __builtin_amdgcn_mfma_f32_16x16x32_bf16(a[kk][i], bcur[kk][j], acc[i][j], 0, 0, 0);
#pragma unroll
    for (int kk = 0; kk < 2; ++kk)
#pragma unroll
      for (int j = 0; j < 2; ++j)
        bcur[kk][j] = bnxt[kk][j];
  }

  // epilogue: D[m][n] at m = quad*4+reg (+16*i), n = l16 (+16*j)
  const int m0 = bm + wm + quad * 4;
  const int n0 = bn + wn + l16;
  const int batch = bm >> 10;         // 128-row tile always within one batch
  float mu = 0.f, rs = 0.f;
  if (EPI == 2) {
    const float s1 = stat_in[batch * 2], s2v = stat_in[batch * 2 + 1];
    mu = s1 * (1.0f / SD_);
    rs = rsqrtf(s2v * (1.0f / SD_) - mu * mu + 1e-5f);
  }
  float ts = 0.f, ts2 = 0.f;
#pragma unroll
  for (int i = 0; i < 4; ++i) {
#pragma unroll
    for (int j = 0; j < 2; ++j) {
      const int n = n0 + j * 16;
#pragma unroll
      for (int r = 0; r < 4; ++r) {
        const int m = m0 + i * 16 + r;
        float v = acc[i][j][r];
        if (EPI == 0) {
          const int t = n / D_;
          const int rr2 = n - t * D_;
          const int hh = rr2 >> 6, dd = rr2 & 63;
          const int bb = m >> 10, ss = m & 1023;
          const long hoff = (long)(bb * H_ + hh);
          if (t == 0)      outb0[(hoff * S_ + ss) * HD_ + dd] = __float2bfloat16(v * QSCALE);
          else if (t == 1) outb1[(hoff * S_ + ss) * HD_ + dd] = __float2bfloat16(v);
          else             outb2[(hoff * HD_ + dd) * S_ + ss] = __float2bfloat16(v);
        } else if (EPI == 1) {
          v += biasf[n] + resf[(long)m * N + n];
          outf[(long)m * N + n] = v;
          outb0[(long)m * N + n] = __float2bfloat16(v);
          if (STATS) { ts += v; ts2 += v * v; }
        } else if (EPI == 2) {
          v = rs * (v - mu * cs[n]) + biasf[n];
          // tanh-form GELU via sigmoid: v * sigm(1.59577(v + 0.044715 v^3))
          float u = v * v;
          float y = v * (1.0f + 0.044715f * u) * 0.7978845608028654f;
          float z = exp2f(y * -2.885390081777927f);        // e^{-2y}
          v = v * __builtin_amdgcn_rcpf(1.0f + z);
          outb0[(long)m * N + n] = __float2bfloat16(v);
        } else {
          v += biasf[n] + resf[(long)m * N + n];
          outf[(long)m * N + n] = v;
        }
      }
    }
  }
  if (STATS) {                        // fused instance-norm partial sums
#pragma unroll
    for (int o = 1; o < 64; o <<= 1) { ts += __shfl_xor(ts, o, 64); ts2 += __shfl_xor(ts2, o, 64); }
    if (lane == 0) { sred[wave * 2] = ts; sred[wave * 2 + 1] = ts2; }
    __syncthreads();
    if (tid == 0) {
      atomicAdd(&statp[batch * 2], sred[0] + sred[2] + sred[4] + sred[6]);
      atomicAdd(&statp[batch * 2 + 1], sred[1] + sred[3] + sred[5] + sred[7]);
    }
  }
}

// ---------------------------------------------------------------------------
// flash attention: grid (B*H, S/64) head-major for XCD L2 locality.
// QK computed as S^T (operands swapped): lane holds one q-row (= l16) x 16 kv.
// -> single per-lane softmax accumulator, P written as packed bf16x4 b64.
// K/V LDS dbuf + XOR chunk swizzle; no-max softmax (q pre-scaled).
// ---------------------------------------------------------------------------
__global__ __launch_bounds__(256) void attn64(const bf16* __restrict__ q,
                                              const bf16* __restrict__ k,
                                              const bf16* __restrict__ vt,
                                              bf16* __restrict__ o) {
  __shared__ __align__(16) bf16 Ks[2][64 * 64];
  __shared__ __align__(16) bf16 Vs[2][64 * 64];   // [d][kv]
  __shared__ __align__(16) bf16 Ps[4 * 16 * 64];  // per-wave private 16x64 [qrow][kv]
  const int bh = blockIdx.x, qt = blockIdx.y;
  const int tid = threadIdx.x, wave = tid >> 6, lane = tid & 63;
  const int quad = lane >> 4, l16 = lane & 15;
  const int sw = (l16 & 7) ^ ((l16 >> 3) & 1);   // swz(row) for rows ≡ l16 (mod 16)
  const long base = (long)bh * (S_ * HD_);
  const bf16* kg = k + base;
  const bf16* vg = vt + base;

  const int srow = tid >> 3;                                    // 0..31
  const int scg = (tid & 7) ^ (srow & 7) ^ ((srow >> 3) & 1);   // global chunk to fetch

  short8 aq[2];
#pragma unroll
  for (int kk = 0; kk < 2; ++kk)
    aq[kk] = *(const short8*)(q + base + (long)(qt * 64 + wave * 16 + l16) * HD_ +
                              kk * 32 + quad * 8);

  gl2lds16(kg + (long)srow * HD_ + scg * 8, &Ks[0][0] + tid * 8);
  gl2lds16(kg + (long)(32 + srow) * HD_ + scg * 8, &Ks[0][0] + 2048 + tid * 8);
  gl2lds16(vg + (long)srow * S_ + scg * 8, &Vs[0][0] + tid * 8);
  gl2lds16(vg + (long)(32 + srow) * S_ + scg * 8, &Vs[0][0] + 2048 + tid * 8);

  f32x4 oacc[4];
#pragma unroll
  for (int j = 0; j < 4; ++j) oacc[j] = (f32x4){0.f, 0.f, 0.f, 0.f};
  float lp = 0.f;                       // per-lane partial sum for q-row l16

  for (int c = 0; c < 16; ++c) {
    const int cur = c & 1;
    __syncthreads();

    // S^T tiles: D[m = kv_local = quad*4+r (+16i)][n = qrow = l16]
    f32x4 s[4];
#pragma unroll
    for (int i = 0; i < 4; ++i) s[i] = (f32x4){0.f, 0.f, 0.f, 0.f};
#pragma unroll
    for (int kk = 0; kk < 2; ++kk) {
#pragma unroll
      for (int i = 0; i < 4; ++i) {
        short8 ak = *(const short8*)(&Ks[cur][0] + (i * 16 + l16) * 64 +
                                     (((kk * 4 + quad) ^ sw) * 8));
        s[i] = __builtin_amdgcn_mfma_f32_16x16x32_bf16(ak, aq[kk], s[i], 0, 0, 0);
      }
    }

    if (c < 15) {
      const int nxt = cur ^ 1;
      gl2lds16(kg + (long)((c + 1) * 64 + srow) * HD_ + scg * 8, &Ks[nxt][0] + tid * 8);
      gl2lds16(kg + (long)((c + 1) * 64 + 32 + srow) * HD_ + scg * 8, &Ks[nxt][0] + 2048 + tid * 8);
      gl2lds16(vg + (long)srow * S_ + (c + 1) * 64 + scg * 8, &Vs[nxt][0] + tid * 8);
      gl2lds16(vg + (long)(32 + srow) * S_ + (c + 1) * 64 + scg * 8, &Vs[nxt][0] + 2048 + tid * 8);
    }

    // softmax: p = 2^s; lane's 16 values all belong to q-row l16.
#pragma unroll
    for (int i = 0; i < 4; ++i) {
      __align__(8) bf16 pk[4];
#pragma unroll
      for (int r = 0; r < 4; ++r) {
        float p = exp2f(s[i][r]);
        lp += p;
        pk[r] = __float2bfloat16(p);
      }
      const int chunk = 2 * i + (quad >> 1);
      *(uint2*)(Ps + wave * 1024 + l16 * 64 + ((chunk ^ sw) * 8) + (quad & 1) * 4) =
          *(const uint2*)pk;
    }

    // PV: wave-private Ps round-trip (lgkmcnt ordering only, no barrier)
#pragma unroll
    for (int kk = 0; kk < 2; ++kk) {
      short8 ap = *(const short8*)(Ps + wave * 1024 + l16 * 64 +
                                   (((kk * 4 + quad) ^ sw) * 8));
#pragma unroll
      for (int dj = 0; dj < 4; ++dj) {
        short8 bv = *(const short8*)(&Vs[cur][0] + (dj * 16 + l16) * 64 +
                                     (((kk * 4 + quad) ^ sw) * 8));
        oacc[dj] = __builtin_amdgcn_mfma_f32_16x16x32_bf16(ap, bv, oacc[dj], 0, 0, 0);
      }
    }
  }

  // reduce row sums: lane's lp covers quad's 16-kv slices; sum across quads
  float lt = lp;
  lt += __shfl_xor(lt, 16, 64);
  lt += __shfl_xor(lt, 32, 64);       // lane now holds full sum for q-row l16

  const int b = bh / H_, hh = bh - b * H_;
#pragma unroll
  for (int r = 0; r < 4; ++r) {
    const float inv = 1.0f / __shfl(lt, quad * 4 + r, 64);
    const int sg = qt * 64 + wave * 16 + quad * 4 + r;
    const long rowoff = ((long)b * S_ + sg) * D_ + hh * HD_;
#pragma unroll
    for (int dj = 0; dj < 4; ++dj)
      o[rowoff + dj * 16 + l16] = __float2bfloat16(oacc[dj][r] * inv);
  }
}

// ---------------------------------------------------------------------------
extern "C" void kernel_launch(void* const* d_in, const int* in_sizes, int n_in,
                              void* d_out, int out_size, void* d_ws, size_t ws_size,
                              hipStream_t stream) {
  const float* x     = (const float*)d_in[0];
  const float* w_qkv = (const float*)d_in[1];
  const float* w_out = (const float*)d_in[2];
  const float* b_out = (const float*)d_in[3];
  const float* w1    = (const float*)d_in[4];
  const float* b1    = (const float*)d_in[5];
  const float* w2    = (const float*)d_in[6];
  const float* b2    = (const float*)d_in[7];
  float* out = (float*)d_out;

  // workspace layout
  bf16* wt_qkv = (bf16*)d_ws;                 // [2304][768]
  bf16* wt_out = wt_qkv + 2304 * 768;         // [768][768]
  bf16* wt1    = wt_out + 768 * 768;          // [3072][768]
  bf16* wt2    = wt1 + 3072 * 768;            // [768][3072]
  bf16* qb     = wt2 + 768 * 3072;            // [B,H,S,HD] = 6291456
  bf16* kb     = qb + 6291456;
  bf16* vtb    = kb + 6291456;                // [B,H,HD,S]
  bf16* ob     = vtb + 6291456;               // attention out [B,S,D] bf16
  float* x1f   = (float*)(ob + 6291456);      // residual-1 fp32 [B,S,D]
  bf16* hb     = (bf16*)(x1f + 6291456);      // norm-1 bf16; later reused as x1b
  float* redp  = (float*)(hb + 6291456);      // 768*2 block partials
  float* red_x = redp + 1536;                 // 16 raw sums (norm-1)
  float* red2  = red_x + 16;                  // 16 raw sums (norm-2, atomics)
  float* cs1   = red2 + 16;                   // colsum(w1)[3072]
  bf16* gb     = qb;                          // MLP hidden reuses qb..ob (dead)
  bf16* x1b    = hb;                          // bf16 copy of x1 (hb dead after QKV)

  // 1. all weight transposes
  transpose_all<<<6912, 256, 0, stream>>>(w_qkv, w_out, w1, w2,
                                          wt_qkv, wt_out, wt1, wt2);

  // 2-4. instance-norm(x) -> hb; colsum(wt1) -> cs1 (fused into stats grid)
  stats_partial<<<768 + 48, 256, 0, stream>>>(x, redp, wt1, cs1);
  stats_final<<<1, 512, 0, stream>>>(redp, red_x, red2);
  norm_k<<<3072, 256, 0, stream>>>(x, red_x, hb);

  // 5. QKV projection with scatter (q pre-scaled by QSCALE)
  gemm_k<0, false><<<dim3(64, 36), 256, 0, stream>>>(
      hb, wt_qkv, 8192, 2304, 768, nullptr, nullptr, nullptr, nullptr,
      nullptr, qb, kb, vtb, nullptr);
  // 6. attention (head-major grid for XCD L2 locality)
  attn64<<<dim3(B_ * H_, 16), 256, 0, stream>>>(qb, kb, vtb, ob);

  // 7. out-projection + bias + residual -> x1f fp32 + x1b bf16, stats -> red2
  gemm_k<1, true><<<dim3(64, 12), 256, 0, stream>>>(
      ob, wt_out, 8192, 768, 768, b_out, x, nullptr, nullptr,
      x1f, x1b, nullptr, nullptr, red2);

  // 8. MLP up on UNNORMALIZED x1b; instance-norm folded into affine epilogue;
  //    tanh-GELU -> gb
  gemm_k<2, false><<<dim3(64, 48), 256, 0, stream>>>(
      x1b, wt1, 8192, 3072, 768, b1, nullptr, cs1, red2,
      nullptr, gb, nullptr, nullptr, nullptr);

  // 9. MLP down + bias + residual -> out
  gemm_k<3, false><<<dim3(64, 12), 256, 0, stream>>>(
      gb, wt2, 8192, 768, 3072, b2, x1f, nullptr, nullptr,
      out, nullptr, nullptr, nullptr, nullptr);
}

// Round 9
// 351.736 us; speedup vs baseline: 1.3333x; 1.3333x over previous
//
#include <hip/hip_runtime.h>
#include <hip/hip_bf16.h>

typedef __hip_bfloat16 bf16;
typedef __attribute__((ext_vector_type(8))) short short8;   // 8 bf16 = 4 VGPRs (MFMA A/B frag)
typedef __attribute__((ext_vector_type(4))) float f32x4;    // MFMA C/D frag

#define B_   8
#define S_   1024
#define D_   768
#define H_   12
#define HD_  64
#define MLP_ 3072
#define SD_  (S_ * D_)          // 786432 elements per batch

#define QSCALE 0.18033688011112042f   // log2(e) / 8  (softmax scale folded into q)

__device__ __forceinline__ float b2f(short h) {
  union { unsigned u; float f; } w;
  w.u = ((unsigned)(unsigned short)h) << 16;
  return w.f;
}

// async global->LDS, 16B per lane; LDS dest must equal wave-uniform base + lane*16B
__device__ __forceinline__ void gl2lds16(const bf16* g, bf16* l) {
  __builtin_amdgcn_global_load_lds(
      (const __attribute__((address_space(1))) unsigned*)(const void*)g,
      (__attribute__((address_space(3))) unsigned*)(void*)l, 16, 0, 0);
}

// ---------------------------------------------------------------------------
// all 4 weight transposes (fp32 [R][C] -> bf16 [C][R]) in one launch
// ---------------------------------------------------------------------------
__global__ __launch_bounds__(256) void transpose_all(
    const float* __restrict__ w_qkv, const float* __restrict__ w_out,
    const float* __restrict__ w1, const float* __restrict__ w2,
    bf16* __restrict__ t_qkv, bf16* __restrict__ t_out,
    bf16* __restrict__ t1, bf16* __restrict__ t2) {
  const int t = blockIdx.x;
  const float* in; bf16* out; int R, C, idx;
  if (t < 1728)      { in = w_qkv; out = t_qkv; R = 768;  C = 2304; idx = t; }
  else if (t < 2304) { in = w_out; out = t_out; R = 768;  C = 768;  idx = t - 1728; }
  else if (t < 4608) { in = w1;    out = t1;    R = 768;  C = 3072; idx = t - 2304; }
  else               { in = w2;    out = t2;    R = 3072; C = 768;  idx = t - 4608; }
  const int nbx = C >> 5;
  const int bx = (idx % nbx) * 32, by = (idx / nbx) * 32;
  __shared__ float tt[32][33];
  const int tx = threadIdx.x & 31, ty = threadIdx.x >> 5;  // ty: 0..7
#pragma unroll
  for (int rr = 0; rr < 32; rr += 8)
    tt[ty + rr][tx] = in[(long)(by + ty + rr) * C + bx + tx];
  __syncthreads();
#pragma unroll
  for (int rr = 0; rr < 32; rr += 8)
    out[(long)(bx + ty + rr) * R + by + tx] = __float2bfloat16(tt[tx][ty + rr]);
}

// ---------------------------------------------------------------------------
// stats partials + bf16 cast of x (768 blocks)  |  colsum(wt1) (48 blocks)
// |  colsum(wt_qkv) (36 blocks). Colsums read bf16 [N][768] rows contiguously.
// ---------------------------------------------------------------------------
__global__ __launch_bounds__(256) void stats_partial(const float* __restrict__ x,
                                                     float* __restrict__ redp,
                                                     const bf16* __restrict__ wt1,
                                                     const bf16* __restrict__ wt_qkv,
                                                     float* __restrict__ cs1,
                                                     float* __restrict__ csq,
                                                     bf16* __restrict__ xb) {
  if (blockIdx.x >= 768) {                       // colsum over K of weight rows
    const bf16* wsrc; float* cdst; int bi;
    if (blockIdx.x < 816) { wsrc = wt1;    cdst = cs1; bi = blockIdx.x - 768; }
    else                  { wsrc = wt_qkv; cdst = csq; bi = blockIdx.x - 816; }
    const int row = bi * 64 + (threadIdx.x >> 2);
    const int part = threadIdx.x & 3;
    const bf16* wr = wsrc + (long)row * 768 + part * 192;
    float s = 0.f;
#pragma unroll
    for (int u = 0; u < 24; ++u) {
      short8 v = *(const short8*)(wr + u * 8);
#pragma unroll
      for (int e = 0; e < 8; ++e) s += b2f(v[e]);
    }
    s += __shfl_xor(s, 1, 64);
    s += __shfl_xor(s, 2, 64);
    if (part == 0) cdst[row] = s;
    return;
  }
  const long off = (long)blockIdx.x * 8192;
  float s = 0.f, s2 = 0.f;
#pragma unroll
  for (int it = 0; it < 4; ++it) {
    const long i = off + ((long)threadIdx.x + it * 256) * 8;
    float4 v0 = *(const float4*)(x + i);
    float4 v1 = *(const float4*)(x + i + 4);
    s += v0.x + v0.y + v0.z + v0.w + v1.x + v1.y + v1.z + v1.w;
    s2 += v0.x * v0.x + v0.y * v0.y + v0.z * v0.z + v0.w * v0.w +
          v1.x * v1.x + v1.y * v1.y + v1.z * v1.z + v1.w * v1.w;
    __align__(16) bf16 tmp[8];
    tmp[0] = __float2bfloat16(v0.x); tmp[1] = __float2bfloat16(v0.y);
    tmp[2] = __float2bfloat16(v0.z); tmp[3] = __float2bfloat16(v0.w);
    tmp[4] = __float2bfloat16(v1.x); tmp[5] = __float2bfloat16(v1.y);
    tmp[6] = __float2bfloat16(v1.z); tmp[7] = __float2bfloat16(v1.w);
    *(short8*)(xb + i) = *(const short8*)tmp;
  }
#pragma unroll
  for (int o = 1; o < 64; o <<= 1) { s += __shfl_xor(s, o, 64); s2 += __shfl_xor(s2, o, 64); }
  __shared__ float sh[8];
  const int wave = threadIdx.x >> 6, lane = threadIdx.x & 63;
  if (lane == 0) { sh[wave * 2] = s; sh[wave * 2 + 1] = s2; }
  __syncthreads();
  if (threadIdx.x == 0) {
    redp[blockIdx.x * 2]     = sh[0] + sh[2] + sh[4] + sh[6];
    redp[blockIdx.x * 2 + 1] = sh[1] + sh[3] + sh[5] + sh[7];
  }
}

// reduce 96 partials per batch -> raw sums red_x[b*2..]; also zero red2
__global__ __launch_bounds__(512) void stats_final(const float* __restrict__ redp,
                                                   float* __restrict__ red_x,
                                                   float* __restrict__ red2) {
  const int b = threadIdx.x >> 6, lane = threadIdx.x & 63;
  const int i0 = (b * 96 + lane) * 2;
  float s  = redp[i0]     + ((lane < 32) ? redp[i0 + 128]     : 0.f);
  float s2 = redp[i0 + 1] + ((lane < 32) ? redp[i0 + 128 + 1] : 0.f);
#pragma unroll
  for (int o = 1; o < 64; o <<= 1) { s += __shfl_xor(s, o, 64); s2 += __shfl_xor(s2, o, 64); }
  if (lane == 0) { red_x[b * 2] = s; red_x[b * 2 + 1] = s2; }
  if (threadIdx.x < 16) red2[threadIdx.x] = 0.f;
}

// ---------------------------------------------------------------------------
// MFMA GEMM: TM=128, TN=64, BK=64, double-buffered LDS (48 KB -> 3 blocks/CU),
// XOR 16B-chunk swizzle on both tiles. (R7 structure — R8's B-direct reverted:
// lane-stride-K B loads are uncoalesced, 64 lines/wave/fragment.)
// EPI 0: IN folded as affine (v = rs*(acc - mu*cs[n])), then QKV scatter
//        (outb0=q*QSCALE [B,H,S,HD], outb1=k, outb2=vT[B,H,HD,S])
// EPI 1: v = acc+bias+res; outf fp32, outb0 bf16 copy (+ fused IN-stats)
// EPI 2: v = rs*(acc - mu*cs[n]) + bias (IN folded); gelu; outb0 bf16
// EPI 3: v = acc+bias+res; outf fp32 only
// ---------------------------------------------------------------------------
template <int EPI, bool STATS>
__global__ __launch_bounds__(256) void gemm_k(
    const bf16* __restrict__ A, const bf16* __restrict__ Bt,
    int M, int N, int K,
    const float* __restrict__ biasf, const float* __restrict__ resf,
    const float* __restrict__ cs, const float* __restrict__ stat_in,
    float* __restrict__ outf,
    bf16* __restrict__ outb0, bf16* __restrict__ outb1, bf16* __restrict__ outb2,
    float* __restrict__ statp) {
  __shared__ __align__(16) bf16 As[2][128 * 64];
  __shared__ __align__(16) bf16 Bs[2][64 * 64];
  __shared__ float sred[8];
  const int tid = threadIdx.x;
  const int bm = blockIdx.x * 128, bn = blockIdx.y * 64;
  const int wave = tid >> 6, lane = tid & 63;
  const int quad = lane >> 4, l16 = lane & 15;
  const int wm = (wave >> 1) * 64, wn = (wave & 1) * 32;
  const int swz = l16 & 7;            // row&7 for all fragment rows

  f32x4 acc[4][2];
#pragma unroll
  for (int i = 0; i < 4; ++i)
#pragma unroll
    for (int j = 0; j < 2; ++j) acc[i][j] = (f32x4){0.f, 0.f, 0.f, 0.f};

  const int srow = tid >> 3;                 // 0..31
  const int sgc = (tid & 7) ^ (srow & 7);    // swizzled global chunk for this LDS slot
  const bf16* Ab = A + (long)(bm + srow) * K + sgc * 8;
  const bf16* Bb = Bt + (long)(bn + srow) * K + sgc * 8;

  auto stage = [&](int buf, int k0) {
#pragma unroll
    for (int s = 0; s < 4; ++s)
      gl2lds16(Ab + (long)(s * 32) * K + k0, &As[buf][0] + s * 2048 + tid * 8);
#pragma unroll
    for (int s = 0; s < 2; ++s)
      gl2lds16(Bb + (long)(s * 32) * K + k0, &Bs[buf][0] + s * 2048 + tid * 8);
  };

  stage(0, 0);
  const int nk = K >> 6;
  for (int kt = 0; kt < nk; ++kt) {
    const int cur = kt & 1;
    __syncthreads();                  // buf[cur] staged (vmcnt drain); buf[cur^1] free
    if (kt + 1 < nk) stage(cur ^ 1, (kt + 1) * 64);
    short8 a[2][4], b[2][2];
#pragma unroll
    for (int kk = 0; kk < 2; ++kk) {
      const int co = ((kk * 4 + quad) ^ swz) * 8;
#pragma unroll
      for (int i = 0; i < 4; ++i)
        a[kk][i] = *(const short8*)(&As[cur][0] + (wm + i * 16 + l16) * 64 + co);
#pragma unroll
      for (int j = 0; j < 2; ++j)
        b[kk][j] = *(const short8*)(&Bs[cur][0] + (wn + j * 16 + l16) * 64 + co);
    }
#pragma unroll
    for (int kk = 0; kk < 2; ++kk)
#pragma unroll
      for (int i = 0; i < 4; ++i)
#pragma unroll
        for (int j = 0; j < 2; ++j)
          acc[i][j] = __builtin_amdgcn_mfma_f32_16x16x32_bf16(a[kk][i], b[kk][j], acc[i][j], 0, 0, 0);
  }

  // epilogue: D[m][n] at m = quad*4+reg (+16*i), n = l16 (+16*j)
  const int m0 = bm + wm + quad * 4;
  const int n0 = bn + wn + l16;
  const int batch = bm >> 10;         // 128-row tile always within one batch
  float mu = 0.f, rs = 0.f;
  if (EPI == 0 || EPI == 2) {
    const float s1 = stat_in[batch * 2], s2v = stat_in[batch * 2 + 1];
    mu = s1 * (1.0f / SD_);
    rs = rsqrtf(s2v * (1.0f / SD_) - mu * mu + 1e-5f);
  }
  float ts = 0.f, ts2 = 0.f;
#pragma unroll
  for (int i = 0; i < 4; ++i) {
#pragma unroll
    for (int j = 0; j < 2; ++j) {
      const int n = n0 + j * 16;
#pragma unroll
      for (int r = 0; r < 4; ++r) {
        const int m = m0 + i * 16 + r;
        float v = acc[i][j][r];
        if (EPI == 0) {
          v = rs * (v - mu * cs[n]);    // instance-norm-1 folded (A was raw x)
          const int t = n / D_;
          const int rr2 = n - t * D_;
          const int hh = rr2 >> 6, dd = rr2 & 63;
          const int bb = m >> 10, ss = m & 1023;
          const long hoff = (long)(bb * H_ + hh);
          if (t == 0)      outb0[(hoff * S_ + ss) * HD_ + dd] = __float2bfloat16(v * QSCALE);
          else if (t == 1) outb1[(hoff * S_ + ss) * HD_ + dd] = __float2bfloat16(v);
          else             outb2[(hoff * HD_ + dd) * S_ + ss] = __float2bfloat16(v);
        } else if (EPI == 1) {
          v += biasf[n] + resf[(long)m * N + n];
          outf[(long)m * N + n] = v;
          outb0[(long)m * N + n] = __float2bfloat16(v);
          if (STATS) { ts += v; ts2 += v * v; }
        } else if (EPI == 2) {
          v = rs * (v - mu * cs[n]) + biasf[n];
          // tanh-form GELU via sigmoid: v * sigm(1.59577(v + 0.044715 v^3))
          float u = v * v;
          float y = v * (1.0f + 0.044715f * u) * 0.7978845608028654f;
          float z = exp2f(y * -2.885390081777927f);        // e^{-2y}
          v = v * __builtin_amdgcn_rcpf(1.0f + z);
          outb0[(long)m * N + n] = __float2bfloat16(v);
        } else {
          v += biasf[n] + resf[(long)m * N + n];
          outf[(long)m * N + n] = v;
        }
      }
    }
  }
  if (STATS) {                        // fused instance-norm partial sums
#pragma unroll
    for (int o = 1; o < 64; o <<= 1) { ts += __shfl_xor(ts, o, 64); ts2 += __shfl_xor(ts2, o, 64); }
    if (lane == 0) { sred[wave * 2] = ts; sred[wave * 2 + 1] = ts2; }
    __syncthreads();
    if (tid == 0) {
      atomicAdd(&statp[batch * 2], sred[0] + sred[2] + sred[4] + sred[6]);
      atomicAdd(&statp[batch * 2 + 1], sred[1] + sred[3] + sred[5] + sred[7]);
    }
  }
}

// ---------------------------------------------------------------------------
// flash attention: grid (B*H, S/64) head-major for XCD L2 locality.
// QK computed as S^T (operands swapped): lane holds one q-row (= l16) x 16 kv.
// -> single per-lane softmax accumulator, P written as packed bf16x4 b64.
// K/V LDS dbuf + XOR chunk swizzle; no-max softmax (q pre-scaled).
// ---------------------------------------------------------------------------
__global__ __launch_bounds__(256) void attn64(const bf16* __restrict__ q,
                                              const bf16* __restrict__ k,
                                              const bf16* __restrict__ vt,
                                              bf16* __restrict__ o) {
  __shared__ __align__(16) bf16 Ks[2][64 * 64];
  __shared__ __align__(16) bf16 Vs[2][64 * 64];   // [d][kv]
  __shared__ __align__(16) bf16 Ps[4 * 16 * 64];  // per-wave private 16x64 [qrow][kv]
  const int bh = blockIdx.x, qt = blockIdx.y;
  const int tid = threadIdx.x, wave = tid >> 6, lane = tid & 63;
  const int quad = lane >> 4, l16 = lane & 15;
  const int sw = (l16 & 7) ^ ((l16 >> 3) & 1);   // swz(row) for rows ≡ l16 (mod 16)
  const long base = (long)bh * (S_ * HD_);
  const bf16* kg = k + base;
  const bf16* vg = vt + base;

  const int srow = tid >> 3;                                    // 0..31
  const int scg = (tid & 7) ^ (srow & 7) ^ ((srow >> 3) & 1);   // global chunk to fetch

  short8 aq[2];
#pragma unroll
  for (int kk = 0; kk < 2; ++kk)
    aq[kk] = *(const short8*)(q + base + (long)(qt * 64 + wave * 16 + l16) * HD_ +
                              kk * 32 + quad * 8);

  gl2lds16(kg + (long)srow * HD_ + scg * 8, &Ks[0][0] + tid * 8);
  gl2lds16(kg + (long)(32 + srow) * HD_ + scg * 8, &Ks[0][0] + 2048 + tid * 8);
  gl2lds16(vg + (long)srow * S_ + scg * 8, &Vs[0][0] + tid * 8);
  gl2lds16(vg + (long)(32 + srow) * S_ + scg * 8, &Vs[0][0] + 2048 + tid * 8);

  f32x4 oacc[4];
#pragma unroll
  for (int j = 0; j < 4; ++j) oacc[j] = (f32x4){0.f, 0.f, 0.f, 0.f};
  float lp = 0.f;                       // per-lane partial sum for q-row l16

  for (int c = 0; c < 16; ++c) {
    const int cur = c & 1;
    __syncthreads();

    // S^T tiles: D[m = kv_local = quad*4+r (+16i)][n = qrow = l16]
    f32x4 s[4];
#pragma unroll
    for (int i = 0; i < 4; ++i) s[i] = (f32x4){0.f, 0.f, 0.f, 0.f};
#pragma unroll
    for (int kk = 0; kk < 2; ++kk) {
#pragma unroll
      for (int i = 0; i < 4; ++i) {
        short8 ak = *(const short8*)(&Ks[cur][0] + (i * 16 + l16) * 64 +
                                     (((kk * 4 + quad) ^ sw) * 8));
        s[i] = __builtin_amdgcn_mfma_f32_16x16x32_bf16(ak, aq[kk], s[i], 0, 0, 0);
      }
    }

    if (c < 15) {
      const int nxt = cur ^ 1;
      gl2lds16(kg + (long)((c + 1) * 64 + srow) * HD_ + scg * 8, &Ks[nxt][0] + tid * 8);
      gl2lds16(kg + (long)((c + 1) * 64 + 32 + srow) * HD_ + scg * 8, &Ks[nxt][0] + 2048 + tid * 8);
      gl2lds16(vg + (long)srow * S_ + (c + 1) * 64 + scg * 8, &Vs[nxt][0] + tid * 8);
      gl2lds16(vg + (long)(32 + srow) * S_ + (c + 1) * 64 + scg * 8, &Vs[nxt][0] + 2048 + tid * 8);
    }

    // softmax: p = 2^s; lane's 16 values all belong to q-row l16.
#pragma unroll
    for (int i = 0; i < 4; ++i) {
      __align__(8) bf16 pk[4];
#pragma unroll
      for (int r = 0; r < 4; ++r) {
        float p = exp2f(s[i][r]);
        lp += p;
        pk[r] = __float2bfloat16(p);
      }
      const int chunk = 2 * i + (quad >> 1);
      *(uint2*)(Ps + wave * 1024 + l16 * 64 + ((chunk ^ sw) * 8) + (quad & 1) * 4) =
          *(const uint2*)pk;
    }

    // PV: wave-private Ps round-trip (lgkmcnt ordering only, no barrier)
#pragma unroll
    for (int kk = 0; kk < 2; ++kk) {
      short8 ap = *(const short8*)(Ps + wave * 1024 + l16 * 64 +
                                   (((kk * 4 + quad) ^ sw) * 8));
#pragma unroll
      for (int dj = 0; dj < 4; ++dj) {
        short8 bv = *(const short8*)(&Vs[cur][0] + (dj * 16 + l16) * 64 +
                                     (((kk * 4 + quad) ^ sw) * 8));
        oacc[dj] = __builtin_amdgcn_mfma_f32_16x16x32_bf16(ap, bv, oacc[dj], 0, 0, 0);
      }
    }
  }

  // reduce row sums: lane's lp covers quad's 16-kv slices; sum across quads
  float lt = lp;
  lt += __shfl_xor(lt, 16, 64);
  lt += __shfl_xor(lt, 32, 64);       // lane now holds full sum for q-row l16

  const int b = bh / H_, hh = bh - b * H_;
#pragma unroll
  for (int r = 0; r < 4; ++r) {
    const float inv = 1.0f / __shfl(lt, quad * 4 + r, 64);
    const int sg = qt * 64 + wave * 16 + quad * 4 + r;
    const long rowoff = ((long)b * S_ + sg) * D_ + hh * HD_;
#pragma unroll
    for (int dj = 0; dj < 4; ++dj)
      o[rowoff + dj * 16 + l16] = __float2bfloat16(oacc[dj][r] * inv);
  }
}

// ---------------------------------------------------------------------------
extern "C" void kernel_launch(void* const* d_in, const int* in_sizes, int n_in,
                              void* d_out, int out_size, void* d_ws, size_t ws_size,
                              hipStream_t stream) {
  const float* x     = (const float*)d_in[0];
  const float* w_qkv = (const float*)d_in[1];
  const float* w_out = (const float*)d_in[2];
  const float* b_out = (const float*)d_in[3];
  const float* w1    = (const float*)d_in[4];
  const float* b1    = (const float*)d_in[5];
  const float* w2    = (const float*)d_in[6];
  const float* b2    = (const float*)d_in[7];
  float* out = (float*)d_out;

  // workspace layout
  bf16* wt_qkv = (bf16*)d_ws;                 // [2304][768]
  bf16* wt_out = wt_qkv + 2304 * 768;         // [768][768]
  bf16* wt1    = wt_out + 768 * 768;          // [3072][768]
  bf16* wt2    = wt1 + 3072 * 768;            // [768][3072]
  bf16* qb     = wt2 + 768 * 3072;            // [B,H,S,HD] = 6291456
  bf16* kb     = qb + 6291456;
  bf16* vtb    = kb + 6291456;                // [B,H,HD,S]
  bf16* ob     = vtb + 6291456;               // attention out [B,S,D] bf16
  float* x1f   = (float*)(ob + 6291456);      // residual-1 fp32 [B,S,D]
  bf16* hb     = (bf16*)(x1f + 6291456);      // xb (bf16 x); later reused as x1b
  float* redp  = (float*)(hb + 6291456);      // 768*2 block partials
  float* red_x = redp + 1536;                 // 16 raw sums (norm-1)
  float* red2  = red_x + 16;                  // 16 raw sums (norm-2, atomics)
  float* cs1   = red2 + 16;                   // colsum(w1)[3072]
  float* csq   = cs1 + 3072;                  // colsum(w_qkv)[2304]
  bf16* gb     = qb;                          // MLP hidden reuses qb..ob (dead)
  bf16* xb     = hb;                          // bf16 cast of x
  bf16* x1b    = hb;                          // bf16 copy of x1 (xb dead after QKV)

  // 1. all weight transposes
  transpose_all<<<6912, 256, 0, stream>>>(w_qkv, w_out, w1, w2,
                                          wt_qkv, wt_out, wt1, wt2);

  // 2-3. stats(x) + bf16 cast -> xb; colsum(wt1) -> cs1; colsum(wt_qkv) -> csq
  stats_partial<<<768 + 48 + 36, 256, 0, stream>>>(x, redp, wt1, wt_qkv,
                                                   cs1, csq, xb);
  stats_final<<<1, 512, 0, stream>>>(redp, red_x, red2);

  // 4. QKV projection on RAW xb; instance-norm-1 folded into epilogue; scatter
  gemm_k<0, false><<<dim3(64, 36), 256, 0, stream>>>(
      xb, wt_qkv, 8192, 2304, 768, nullptr, nullptr, csq, red_x,
      nullptr, qb, kb, vtb, nullptr);
  // 5. attention (head-major grid for XCD L2 locality)
  attn64<<<dim3(B_ * H_, 16), 256, 0, stream>>>(qb, kb, vtb, ob);

  // 6. out-projection + bias + residual -> x1f fp32 + x1b bf16, stats -> red2
  gemm_k<1, true><<<dim3(64, 12), 256, 0, stream>>>(
      ob, wt_out, 8192, 768, 768, b_out, x, nullptr, nullptr,
      x1f, x1b, nullptr, nullptr, red2);

  // 7. MLP up on UNNORMALIZED x1b; instance-norm-2 folded; tanh-GELU -> gb
  gemm_k<2, false><<<dim3(64, 48), 256, 0, stream>>>(
      x1b, wt1, 8192, 3072, 768, b1, nullptr, cs1, red2,
      nullptr, gb, nullptr, nullptr, nullptr);

  // 8. MLP down + bias + residual -> out
  gemm_k<3, false><<<dim3(64, 12), 256, 0, stream>>>(
      gb, wt2, 8192, 768, 3072, b2, x1f, nullptr, nullptr,
      out, nullptr, nullptr, nullptr, nullptr);
}